// Round 4
// baseline (1465.880 us; speedup 1.0000x reference)
//
#include <hip/hip_runtime.h>
#include <hip/hip_bf16.h>
#include <math.h>

#define B_ 64
#define NM_ 120
#define NE_ 60
#define NS_ 18
#define NV_ 2
#define N_NODE 200
#define N_TOTAL 12800
#define D_ENC 768
#define D_TYPE 128
#define D_ 896
#define N_EDGE 409600
#define NUM_LAYERS 4
#define ENT_OUT (B_ * NE_ * D_)   // 3,440,640 floats

typedef __attribute__((ext_vector_type(8))) short short8v;   // 8 bf16 = 4 VGPR
typedef __attribute__((ext_vector_type(4))) float f32x4;

// fp32 -> bf16 round-to-nearest-even (bits)
__device__ __forceinline__ ushort f2bf_rne(float x) {
    unsigned u = __builtin_bit_cast(unsigned, x);
    unsigned r = (u + 0x7FFFu + ((u >> 16) & 1u)) >> 16;
    return (ushort)r;
}
__device__ __forceinline__ float bf2f(ushort h) {
    unsigned u = ((unsigned)h) << 16;
    return __builtin_bit_cast(float, u);
}

// ---------------------------------------------------------------------------
// 1. Build node features h0 = concat(hidden, type_emb)  (12800 x 896)
// ---------------------------------------------------------------------------
__global__ void build_nodes(const float* __restrict__ men, const float* __restrict__ ent,
                            const float* __restrict__ sen, const float* __restrict__ vir,
                            const float* __restrict__ te, float* __restrict__ h0) {
    int i = blockIdx.x;            // node id 0..12799
    int t = threadIdx.x;           // 128 threads, 7 elems each
    int b = i / N_NODE, n = i % N_NODE;
    const float* src; int typ;
    if (n < NM_)            { src = men + (size_t)(b * NM_ + n) * D_ENC;          typ = 0; }
    else if (n < NM_ + NE_) { src = ent + (size_t)(b * NE_ + (n - NM_)) * D_ENC;  typ = 1; }
    else if (n < NM_ + NE_ + NS_) { src = sen + (size_t)(b * NS_ + (n - NM_ - NE_)) * D_ENC; typ = 2; }
    else                    { src = vir + (size_t)(b * NV_ + (n - NM_ - NE_ - NS_)) * D_ENC; typ = 3; }
    float* o = h0 + (size_t)i * D_;
    #pragma unroll
    for (int k = 0; k < 7; k++) {
        int d = t + k * 128;
        float v = (d < D_ENC) ? src[d] : te[typ * D_TYPE + (d - D_ENC)];
        o[d] = v;
    }
}

// ---------------------------------------------------------------------------
// 2. CSR construction: degree histogram -> scan -> scatter
// ---------------------------------------------------------------------------
__global__ void count_deg(const int* __restrict__ dst, int* __restrict__ cnt) {
    int e = blockIdx.x * 256 + threadIdx.x;
    if (e < N_EDGE) atomicAdd(&cnt[dst[e]], 1);
}

__global__ void scan_kernel(const int* __restrict__ cnt, int* __restrict__ offs,
                            float* __restrict__ dis) {
    __shared__ int lds[1024];
    int t = threadIdx.x;
    int base = t * 13;
    int local[13];
    int sum = 0;
    #pragma unroll
    for (int k = 0; k < 13; k++) {
        int idx = base + k;
        int v = (idx < N_TOTAL) ? cnt[idx] : 0;
        local[k] = sum;
        sum += v;
    }
    lds[t] = sum;
    __syncthreads();
    for (int off = 1; off < 1024; off <<= 1) {
        int v = lds[t];
        int add = (t >= off) ? lds[t - off] : 0;
        __syncthreads();
        lds[t] = v + add;
        __syncthreads();
    }
    int excl = lds[t] - sum;
    #pragma unroll
    for (int k = 0; k < 13; k++) {
        int idx = base + k;
        if (idx < N_TOTAL) {
            offs[idx] = excl + local[k];
            dis[idx] = rsqrtf((float)(cnt[idx] + 1));   // deg includes self loop
        }
    }
    if (t == 1023) offs[N_TOTAL] = excl + sum;
}

__global__ void fill_csr(const int* __restrict__ src, const int* __restrict__ dst,
                         const int* __restrict__ offs, int* __restrict__ cursor,
                         int* __restrict__ csr_src) {
    int e = blockIdx.x * 256 + threadIdx.x;
    if (e < N_EDGE) {
        int d = dst[e];
        int pos = atomicAdd(&cursor[d], 1);
        csr_src[offs[d] + pos] = src[e];
    }
}

// ---------------------------------------------------------------------------
// 2b. W^T split: WT_hi/lo[l][n][k] (bf16) from W[l][k][n] (fp32), LDS-tiled
//     grid = 4 layers * 14 * 14 tiles of 64x64, 256 threads
// ---------------------------------------------------------------------------
__global__ __launch_bounds__(256) void make_wt(const float* __restrict__ W,
                                               ushort* __restrict__ WT_hi,
                                               ushort* __restrict__ WT_lo) {
    __shared__ float lds[64][65];
    int bid = blockIdx.x;
    int l = bid / 196; int rem = bid % 196;
    int tk = rem / 14, tn = rem % 14;
    const float* Wl = W + (size_t)l * D_ * D_;
    int t = threadIdx.x;
    #pragma unroll
    for (int q = 0; q < 16; q++) {
        int id = q * 256 + t;
        int kk = id >> 6, nn = id & 63;
        lds[kk][nn] = Wl[(size_t)(tk * 64 + kk) * D_ + tn * 64 + nn];
    }
    __syncthreads();
    #pragma unroll
    for (int q = 0; q < 16; q++) {
        int id = q * 256 + t;
        int nn = id >> 6, kk = id & 63;
        float x = lds[kk][nn];
        ushort hi = f2bf_rne(x);
        ushort lo = f2bf_rne(x - bf2f(hi));
        size_t o = (size_t)l * D_ * D_ + (size_t)(tn * 64 + nn) * D_ + tk * 64 + kk;
        WT_hi[o] = hi; WT_lo[o] = lo;
    }
}

// ---------------------------------------------------------------------------
// 3. SpMM + support:  S[i,:] = 0.9*dis[i]*(sum_e dis[src]*h[src,:] + dis[i]*h[i,:]) + 0.1*h0[i,:]
// ---------------------------------------------------------------------------
__global__ __launch_bounds__(256) void spmm_support(
        const float* __restrict__ hin, const float* __restrict__ h0,
        const float* __restrict__ dis, const int* __restrict__ offs,
        const int* __restrict__ csr_src, float* __restrict__ S) {
    int i = blockIdx.x;
    int t = threadIdx.x;
    __shared__ int s_idx[256];
    __shared__ float s_w[256];
    int e0 = offs[i], e1 = offs[i + 1];
    float di = dis[i];
    bool active = t < 224;
    float4 acc = make_float4(0.f, 0.f, 0.f, 0.f);
    if (active) {
        float4 hv = ((const float4*)(hin + (size_t)i * D_))[t];   // self loop
        acc.x = di * hv.x; acc.y = di * hv.y; acc.z = di * hv.z; acc.w = di * hv.w;
    }
    for (int c = e0; c < e1; c += 256) {
        int n = e1 - c; if (n > 256) n = 256;
        if (t < n) { int s = csr_src[c + t]; s_idx[t] = s; s_w[t] = dis[s]; }
        __syncthreads();
        if (active) {
            #pragma unroll 4
            for (int j = 0; j < n; j++) {
                const float4* hp = (const float4*)(hin + (size_t)s_idx[j] * D_);
                float w = s_w[j];
                float4 hv = hp[t];
                acc.x += w * hv.x; acc.y += w * hv.y;
                acc.z += w * hv.z; acc.w += w * hv.w;
            }
        }
        __syncthreads();
    }
    if (active) {
        float4 h0v = ((const float4*)(h0 + (size_t)i * D_))[t];
        float4 o;
        o.x = 0.9f * di * acc.x + 0.1f * h0v.x;
        o.y = 0.9f * di * acc.y + 0.1f * h0v.y;
        o.z = 0.9f * di * acc.z + 0.1f * h0v.z;
        o.w = 0.9f * di * acc.w + 0.1f * h0v.w;
        ((float4*)(S + (size_t)i * D_))[t] = o;
    }
}

// ---------------------------------------------------------------------------
// 4. Split-bf16 MFMA GEMM + affine + relu.
//    H = relu((1-beta)*S + beta*(S@W)), S@W via 3-product bf16 split:
//    S_hi*W_hi + S_hi*W_lo + S_lo*W_hi  (error ~2^-18, "3xTF32" style).
//    Block 128x128, BK=32, 4 waves (2x2), each wave 64x64 = 4x4 mfma 16x16x32.
//    A staged from fp32 S with fused hi/lo split; B staged from precomputed
//    WT_hi/lo [n][k] bf16 (so LDS B-tile is a coalesced vector copy).
//    LDS rows padded to 40 bf16 (80 B) to break bank-conflict pattern.
// ---------------------------------------------------------------------------
__global__ __launch_bounds__(256) void gemm_mfma(
        const float* __restrict__ S, const ushort* __restrict__ WT_hi,
        const ushort* __restrict__ WT_lo, float* __restrict__ H,
        float bcoef, float beta) {
    __shared__ __align__(16) ushort As_hi[128 * 40];
    __shared__ __align__(16) ushort As_lo[128 * 40];
    __shared__ __align__(16) ushort Bs_hi[128 * 40];
    __shared__ __align__(16) ushort Bs_lo[128 * 40];

    int t = threadIdx.x;
    int tile_n = blockIdx.x % 7;
    int tile_m = blockIdx.x / 7;
    int row0 = tile_m * 128, col0 = tile_n * 128;

    int lane = t & 63, w = t >> 6;
    int wm = w >> 1, wn = w & 1;          // 2x2 wave grid, each 64x64 output
    int lrow = lane & 15, lg = lane >> 4; // MFMA fragment coords

    f32x4 acc[4][4];
    #pragma unroll
    for (int i = 0; i < 4; i++)
        #pragma unroll
        for (int j = 0; j < 4; j++) acc[i][j] = (f32x4){0.f, 0.f, 0.f, 0.f};

    for (int k0 = 0; k0 < D_; k0 += 32) {
        // ---- stage A: 128 rows x 32 k fp32 -> hi/lo bf16, layout [m][40]
        #pragma unroll
        for (int q = 0; q < 4; q++) {
            int id = q * 256 + t;          // 0..1023
            int r = id >> 3;               // 0..127
            int kq = id & 7;               // float4 index within row
            float4 v = *(const float4*)(S + (size_t)(row0 + r) * D_ + k0 + kq * 4);
            ushort hx = f2bf_rne(v.x), hy = f2bf_rne(v.y), hz = f2bf_rne(v.z), hw = f2bf_rne(v.w);
            ushort lx = f2bf_rne(v.x - bf2f(hx)), ly = f2bf_rne(v.y - bf2f(hy));
            ushort lz = f2bf_rne(v.z - bf2f(hz)), lw = f2bf_rne(v.w - bf2f(hw));
            int o = r * 40 + kq * 4;       // byte offset 80r+8kq -> 8B aligned
            *(ushort4*)&As_hi[o] = make_ushort4(hx, hy, hz, hw);
            *(ushort4*)&As_lo[o] = make_ushort4(lx, ly, lz, lw);
        }
        // ---- stage B: WT_hi/lo [n][k] bf16, 128 n-rows x 32 k, layout [n][40]
        #pragma unroll
        for (int q = 0; q < 2; q++) {
            int id = q * 256 + t;          // 0..511
            int r = id >> 2;               // n-row 0..127
            int seg = id & 3;              // 8-bf16 segment
            size_t gsrc = (size_t)(col0 + r) * D_ + k0 + seg * 8;
            int o = r * 40 + seg * 8;      // byte offset 80r+16seg -> 16B aligned
            *(short8v*)&Bs_hi[o] = *(const short8v*)(WT_hi + gsrc);
            *(short8v*)&Bs_lo[o] = *(const short8v*)(WT_lo + gsrc);
        }
        __syncthreads();

        // ---- compute: 48 MFMA per wave per k-step
        short8v a_hi[4], a_lo[4];
        #pragma unroll
        for (int fm = 0; fm < 4; fm++) {
            int o = (wm * 64 + fm * 16 + lrow) * 40 + lg * 8;  // 16B aligned
            a_hi[fm] = *(const short8v*)&As_hi[o];
            a_lo[fm] = *(const short8v*)&As_lo[o];
        }
        #pragma unroll
        for (int fn = 0; fn < 4; fn++) {
            int o = (wn * 64 + fn * 16 + lrow) * 40 + lg * 8;
            short8v b_hi = *(const short8v*)&Bs_hi[o];
            short8v b_lo = *(const short8v*)&Bs_lo[o];
            #pragma unroll
            for (int fm = 0; fm < 4; fm++) {
                acc[fm][fn] = __builtin_amdgcn_mfma_f32_16x16x32_bf16(a_hi[fm], b_hi, acc[fm][fn], 0, 0, 0);
                acc[fm][fn] = __builtin_amdgcn_mfma_f32_16x16x32_bf16(a_hi[fm], b_lo, acc[fm][fn], 0, 0, 0);
                acc[fm][fn] = __builtin_amdgcn_mfma_f32_16x16x32_bf16(a_lo[fm], b_hi, acc[fm][fn], 0, 0, 0);
            }
        }
        __syncthreads();
    }

    // ---- epilogue: relu((1-beta)*S + beta*acc)
    // C/D layout (HW-verified): row = lg*4 + reg, col = lrow
    #pragma unroll
    for (int fm = 0; fm < 4; fm++) {
        #pragma unroll
        for (int fn = 0; fn < 4; fn++) {
            #pragma unroll
            for (int r = 0; r < 4; r++) {
                int m = row0 + wm * 64 + fm * 16 + lg * 4 + r;
                int n = col0 + wn * 64 + fn * 16 + lrow;
                float sv = S[(size_t)m * D_ + n];
                H[(size_t)m * D_ + n] = fmaxf(bcoef * sv + beta * acc[fm][fn][r], 0.f);
            }
        }
    }
}

// ---------------------------------------------------------------------------
// 5. Entity slice: out[:ENT_OUT] = h[:, 120:180, :]
// ---------------------------------------------------------------------------
__global__ void write_entity(const float* __restrict__ h, float* __restrict__ out) {
    int idx = blockIdx.x;           // 0 .. B*NE-1
    int t = threadIdx.x;            // 128 threads, 7 each
    int b = idx / NE_, e = idx % NE_;
    const float* src = h + (size_t)(b * N_NODE + NM_ + e) * D_;
    float* dst = out + (size_t)idx * D_;
    #pragma unroll
    for (int k = 0; k < 7; k++) dst[t + k * 128] = src[t + k * 128];
}

// ---------------------------------------------------------------------------
extern "C" void kernel_launch(void* const* d_in, const int* in_sizes, int n_in,
                              void* d_out, int out_size, void* d_ws, size_t ws_size,
                              hipStream_t stream) {
    const float* men = (const float*)d_in[0];
    const float* ent = (const float*)d_in[1];
    const float* sen = (const float*)d_in[2];
    const float* vir = (const float*)d_in[3];
    const float* te  = (const float*)d_in[4];
    const float* gw  = (const float*)d_in[5];
    const int* esrc  = (const int*)d_in[6];
    const int* edst  = (const int*)d_in[7];
    float* out = (float*)d_out;
    float* h = out + ENT_OUT;       // the "out" tuple element doubles as the h buffer

    // workspace layout (~106.4 MB)
    char* ws = (char*)d_ws;
    size_t hbytes = (size_t)N_TOTAL * D_ * sizeof(float);   // 45,875,200
    size_t wtbytes = (size_t)NUM_LAYERS * D_ * D_ * sizeof(ushort); // 6,422,528
    float* h0    = (float*)ws;                ws += hbytes;
    float* S     = (float*)ws;                ws += hbytes;
    ushort* wthi = (ushort*)ws;               ws += wtbytes;
    ushort* wtlo = (ushort*)ws;               ws += wtbytes;
    int* cnt     = (int*)ws;                  ws += N_TOTAL * sizeof(int);
    int* cursor  = (int*)ws;                  ws += N_TOTAL * sizeof(int);
    int* offs    = (int*)ws;                  ws += (N_TOTAL + 1) * sizeof(int);
    int* csr     = (int*)ws;                  ws += (size_t)N_EDGE * sizeof(int);
    float* dis   = (float*)ws;                ws += N_TOTAL * sizeof(float);

    hipMemsetAsync(cnt, 0, 2 * N_TOTAL * sizeof(int), stream);   // cnt + cursor contiguous

    make_wt<<<NUM_LAYERS * 196, 256, 0, stream>>>(gw, wthi, wtlo);
    build_nodes<<<N_TOTAL, 128, 0, stream>>>(men, ent, sen, vir, te, h0);
    count_deg<<<(N_EDGE + 255) / 256, 256, 0, stream>>>(edst, cnt);
    scan_kernel<<<1, 1024, 0, stream>>>(cnt, offs, dis);
    fill_csr<<<(N_EDGE + 255) / 256, 256, 0, stream>>>(esrc, edst, offs, cursor, csr);

    for (int l = 0; l < NUM_LAYERS; l++) {
        double beta_d = log(0.5 / (l + 1) + 1.0);
        float beta = (float)beta_d;
        float bcoef = (float)(1.0 - beta_d);
        const float* hin = (l == 0) ? h0 : h;
        spmm_support<<<N_TOTAL, 256, 0, stream>>>(hin, h0, dis, offs, csr, S);
        gemm_mfma<<<100 * 7, 256, 0, stream>>>(S, wthi + (size_t)l * D_ * D_,
                                               wtlo + (size_t)l * D_ * D_, h, bcoef, beta);
    }
    write_entity<<<B_ * NE_, 128, 0, stream>>>(h, out);
}

// Round 10
// 1364.395 us; speedup vs baseline: 1.0744x; 1.0744x over previous
//
#include <hip/hip_runtime.h>
#include <hip/hip_bf16.h>
#include <math.h>

#define B_ 64
#define NM_ 120
#define NE_ 60
#define NS_ 18
#define NV_ 2
#define N_NODE 200
#define N_TOTAL 12800
#define D_ENC 768
#define D_TYPE 128
#define D_ 896
#define N_EDGE 409600
#define NUM_LAYERS 4
#define ENT_OUT (B_ * NE_ * D_)   // 3,440,640 floats

typedef __attribute__((ext_vector_type(8))) short short8v;   // 8 bf16 = 4 VGPR
typedef __attribute__((ext_vector_type(4))) float f32x4;

// fp32 -> bf16 round-to-nearest-even (bits)
__device__ __forceinline__ ushort f2bf_rne(float x) {
    unsigned u = __builtin_bit_cast(unsigned, x);
    unsigned r = (u + 0x7FFFu + ((u >> 16) & 1u)) >> 16;
    return (ushort)r;
}
__device__ __forceinline__ float bf2f(ushort h) {
    unsigned u = ((unsigned)h) << 16;
    return __builtin_bit_cast(float, u);
}

// ---------------------------------------------------------------------------
// 1. Build node features h0 = concat(hidden, type_emb)  (12800 x 896)
// ---------------------------------------------------------------------------
__global__ void build_nodes(const float* __restrict__ men, const float* __restrict__ ent,
                            const float* __restrict__ sen, const float* __restrict__ vir,
                            const float* __restrict__ te, float* __restrict__ h0) {
    int i = blockIdx.x;            // node id 0..12799
    int t = threadIdx.x;           // 128 threads, 7 elems each
    int b = i / N_NODE, n = i % N_NODE;
    const float* src; int typ;
    if (n < NM_)            { src = men + (size_t)(b * NM_ + n) * D_ENC;          typ = 0; }
    else if (n < NM_ + NE_) { src = ent + (size_t)(b * NE_ + (n - NM_)) * D_ENC;  typ = 1; }
    else if (n < NM_ + NE_ + NS_) { src = sen + (size_t)(b * NS_ + (n - NM_ - NE_)) * D_ENC; typ = 2; }
    else                    { src = vir + (size_t)(b * NV_ + (n - NM_ - NE_ - NS_)) * D_ENC; typ = 3; }
    float* o = h0 + (size_t)i * D_;
    #pragma unroll
    for (int k = 0; k < 7; k++) {
        int d = t + k * 128;
        float v = (d < D_ENC) ? src[d] : te[typ * D_TYPE + (d - D_ENC)];
        o[d] = v;
    }
}

// ---------------------------------------------------------------------------
// 2. CSR construction: degree histogram -> scan -> scatter
// ---------------------------------------------------------------------------
__global__ void count_deg(const int* __restrict__ dst, int* __restrict__ cnt) {
    int e = blockIdx.x * 256 + threadIdx.x;
    if (e < N_EDGE) atomicAdd(&cnt[dst[e]], 1);
}

__global__ void scan_kernel(const int* __restrict__ cnt, int* __restrict__ offs,
                            float* __restrict__ dis) {
    __shared__ int lds[1024];
    int t = threadIdx.x;
    int base = t * 13;
    int local[13];
    int sum = 0;
    #pragma unroll
    for (int k = 0; k < 13; k++) {
        int idx = base + k;
        int v = (idx < N_TOTAL) ? cnt[idx] : 0;
        local[k] = sum;
        sum += v;
    }
    lds[t] = sum;
    __syncthreads();
    for (int off = 1; off < 1024; off <<= 1) {
        int v = lds[t];
        int add = (t >= off) ? lds[t - off] : 0;
        __syncthreads();
        lds[t] = v + add;
        __syncthreads();
    }
    int excl = lds[t] - sum;
    #pragma unroll
    for (int k = 0; k < 13; k++) {
        int idx = base + k;
        if (idx < N_TOTAL) {
            offs[idx] = excl + local[k];
            dis[idx] = rsqrtf((float)(cnt[idx] + 1));   // deg includes self loop
        }
    }
    if (t == 1023) offs[N_TOTAL] = excl + sum;
}

__global__ void fill_csr(const int* __restrict__ src, const int* __restrict__ dst,
                         const int* __restrict__ offs, int* __restrict__ cursor,
                         int* __restrict__ csr_src) {
    int e = blockIdx.x * 256 + threadIdx.x;
    if (e < N_EDGE) {
        int d = dst[e];
        int pos = atomicAdd(&cursor[d], 1);
        csr_src[offs[d] + pos] = src[e];
    }
}

// ---------------------------------------------------------------------------
// 2b. W^T split: WT_hi/lo[l][n][k] (bf16) from W[l][k][n] (fp32), LDS-tiled
// ---------------------------------------------------------------------------
__global__ __launch_bounds__(256) void make_wt(const float* __restrict__ W,
                                               ushort* __restrict__ WT_hi,
                                               ushort* __restrict__ WT_lo) {
    __shared__ float lds[64][65];
    int bid = blockIdx.x;
    int l = bid / 196; int rem = bid % 196;
    int tk = rem / 14, tn = rem % 14;
    const float* Wl = W + (size_t)l * D_ * D_;
    int t = threadIdx.x;
    #pragma unroll
    for (int q = 0; q < 16; q++) {
        int id = q * 256 + t;
        int kk = id >> 6, nn = id & 63;
        lds[kk][nn] = Wl[(size_t)(tk * 64 + kk) * D_ + tn * 64 + nn];
    }
    __syncthreads();
    #pragma unroll
    for (int q = 0; q < 16; q++) {
        int id = q * 256 + t;
        int nn = id >> 6, kk = id & 63;
        float x = lds[kk][nn];
        ushort hi = f2bf_rne(x);
        ushort lo = f2bf_rne(x - bf2f(hi));
        size_t o = (size_t)l * D_ * D_ + (size_t)(tn * 64 + nn) * D_ + tk * 64 + kk;
        WT_hi[o] = hi; WT_lo[o] = lo;
    }
}

// ---------------------------------------------------------------------------
// 3. SpMM + support. Output is the hi/lo bf16 split of S (same bytes as fp32):
//    S[i,:] = 0.9*dis[i]*(sum_e dis[src]*h[src,:] + dis[i]*h[i,:]) + 0.1*h0[i,:]
//    h0 read is nontemporal (streaming; keep L3 for the gather table hin).
//    Gather loop unroll 8: more outstanding loads (latency-bound per r4 PMC).
// ---------------------------------------------------------------------------
__global__ __launch_bounds__(256) void spmm_support(
        const float* __restrict__ hin, const float* __restrict__ h0,
        const float* __restrict__ dis, const int* __restrict__ offs,
        const int* __restrict__ csr_src,
        ushort* __restrict__ S_hi, ushort* __restrict__ S_lo) {
    int i = blockIdx.x;
    int t = threadIdx.x;
    __shared__ int s_idx[256];
    __shared__ float s_w[256];
    int e0 = offs[i], e1 = offs[i + 1];
    float di = dis[i];
    bool active = t < 224;
    float4 acc = make_float4(0.f, 0.f, 0.f, 0.f);
    if (active) {
        float4 hv = ((const float4*)(hin + (size_t)i * D_))[t];   // self loop
        acc.x = di * hv.x; acc.y = di * hv.y; acc.z = di * hv.z; acc.w = di * hv.w;
    }
    for (int c = e0; c < e1; c += 256) {
        int n = e1 - c; if (n > 256) n = 256;
        if (t < n) { int s = csr_src[c + t]; s_idx[t] = s; s_w[t] = dis[s]; }
        __syncthreads();
        if (active) {
            #pragma unroll 8
            for (int j = 0; j < n; j++) {
                const float4* hp = (const float4*)(hin + (size_t)s_idx[j] * D_);
                float w = s_w[j];
                float4 hv = hp[t];
                acc.x += w * hv.x; acc.y += w * hv.y;
                acc.z += w * hv.z; acc.w += w * hv.w;
            }
        }
        __syncthreads();
    }
    if (active) {
        f32x4 h0v = __builtin_nontemporal_load((const f32x4*)(h0 + (size_t)i * D_) + t);
        float ox = 0.9f * di * acc.x + 0.1f * h0v[0];
        float oy = 0.9f * di * acc.y + 0.1f * h0v[1];
        float oz = 0.9f * di * acc.z + 0.1f * h0v[2];
        float ow = 0.9f * di * acc.w + 0.1f * h0v[3];
        ushort hx = f2bf_rne(ox), hy = f2bf_rne(oy), hz = f2bf_rne(oz), hw = f2bf_rne(ow);
        ushort lx = f2bf_rne(ox - bf2f(hx)), ly = f2bf_rne(oy - bf2f(hy));
        ushort lz = f2bf_rne(oz - bf2f(hz)), lw = f2bf_rne(ow - bf2f(hw));
        *(ushort4*)(S_hi + (size_t)i * D_ + 4 * t) = make_ushort4(hx, hy, hz, hw);
        *(ushort4*)(S_lo + (size_t)i * D_ + 4 * t) = make_ushort4(lx, ly, lz, lw);
    }
}

// ---------------------------------------------------------------------------
// 4. Split-bf16 MFMA GEMM + affine + relu. A/B both pre-split in global bf16,
//    staging is pure vector copy (no conversion VALU). 3-product split GEMM:
//    S_hi*W_hi + S_hi*W_lo + S_lo*W_hi. Epilogue S reconstructed = hi+lo.
//    Bijective XCD swizzle (700 = 4*88 + 4*87) so the 7 blocks per S-panel
//    share one XCD's L2.
// ---------------------------------------------------------------------------
__global__ __launch_bounds__(256) void gemm_mfma(
        const ushort* __restrict__ S_hi, const ushort* __restrict__ S_lo,
        const ushort* __restrict__ WT_hi, const ushort* __restrict__ WT_lo,
        float* __restrict__ H, float bcoef, float beta) {
    __shared__ __align__(16) ushort As_hi[128 * 40];
    __shared__ __align__(16) ushort As_lo[128 * 40];
    __shared__ __align__(16) ushort Bs_hi[128 * 40];
    __shared__ __align__(16) ushort Bs_lo[128 * 40];

    int t = threadIdx.x;
    int b0 = blockIdx.x;
    int xcd = b0 & 7, pos = b0 >> 3;                       // grid=700, 700%8!=0:
    int wgid = (xcd < 4 ? xcd * 88 : 352 + (xcd - 4) * 87) + pos;  // bijective (m204)
    int tile_n = wgid % 7;
    int tile_m = wgid / 7;
    int row0 = tile_m * 128, col0 = tile_n * 128;

    int lane = t & 63, w = t >> 6;
    int wm = w >> 1, wn = w & 1;          // 2x2 wave grid, each 64x64 output
    int lrow = lane & 15, lg = lane >> 4; // MFMA fragment coords

    f32x4 acc[4][4];
    #pragma unroll
    for (int i = 0; i < 4; i++)
        #pragma unroll
        for (int j = 0; j < 4; j++) acc[i][j] = (f32x4){0.f, 0.f, 0.f, 0.f};

    for (int k0 = 0; k0 < D_; k0 += 32) {
        // ---- stage A: 128 rows x 32 k bf16 hi/lo, layout [m][40] (pad kills conflicts)
        #pragma unroll
        for (int q = 0; q < 2; q++) {
            int id = q * 256 + t;          // 0..511
            int r = id >> 2;               // row 0..127
            int seg = id & 3;              // 8-bf16 segment
            size_t g = (size_t)(row0 + r) * D_ + k0 + seg * 8;
            int o = r * 40 + seg * 8;
            *(short8v*)&As_hi[o] = *(const short8v*)(S_hi + g);
            *(short8v*)&As_lo[o] = *(const short8v*)(S_lo + g);
        }
        // ---- stage B: WT [n][k] bf16 hi/lo, layout [n][40]
        #pragma unroll
        for (int q = 0; q < 2; q++) {
            int id = q * 256 + t;
            int r = id >> 2;
            int seg = id & 3;
            size_t g = (size_t)(col0 + r) * D_ + k0 + seg * 8;
            int o = r * 40 + seg * 8;
            *(short8v*)&Bs_hi[o] = *(const short8v*)(WT_hi + g);
            *(short8v*)&Bs_lo[o] = *(const short8v*)(WT_lo + g);
        }
        __syncthreads();

        // ---- compute: 48 MFMA per wave per k-step
        short8v a_hi[4], a_lo[4];
        #pragma unroll
        for (int fm = 0; fm < 4; fm++) {
            int o = (wm * 64 + fm * 16 + lrow) * 40 + lg * 8;
            a_hi[fm] = *(const short8v*)&As_hi[o];
            a_lo[fm] = *(const short8v*)&As_lo[o];
        }
        #pragma unroll
        for (int fn = 0; fn < 4; fn++) {
            int o = (wn * 64 + fn * 16 + lrow) * 40 + lg * 8;
            short8v b_hi = *(const short8v*)&Bs_hi[o];
            short8v b_lo = *(const short8v*)&Bs_lo[o];
            #pragma unroll
            for (int fm = 0; fm < 4; fm++) {
                acc[fm][fn] = __builtin_amdgcn_mfma_f32_16x16x32_bf16(a_hi[fm], b_hi, acc[fm][fn], 0, 0, 0);
                acc[fm][fn] = __builtin_amdgcn_mfma_f32_16x16x32_bf16(a_hi[fm], b_lo, acc[fm][fn], 0, 0, 0);
                acc[fm][fn] = __builtin_amdgcn_mfma_f32_16x16x32_bf16(a_lo[fm], b_hi, acc[fm][fn], 0, 0, 0);
            }
        }
        __syncthreads();
    }

    // ---- epilogue: relu((1-beta)*(hi+lo) + beta*acc)
    // C/D layout (HW-verified): row = lg*4 + reg, col = lrow
    #pragma unroll
    for (int fm = 0; fm < 4; fm++) {
        #pragma unroll
        for (int fn = 0; fn < 4; fn++) {
            #pragma unroll
            for (int r = 0; r < 4; r++) {
                int m = row0 + wm * 64 + fm * 16 + lg * 4 + r;
                int n = col0 + wn * 64 + fn * 16 + lrow;
                size_t off = (size_t)m * D_ + n;
                float sv = bf2f(S_hi[off]) + bf2f(S_lo[off]);
                H[off] = fmaxf(bcoef * sv + beta * acc[fm][fn][r], 0.f);
            }
        }
    }
}

// ---------------------------------------------------------------------------
// 5. Entity slice: out[:ENT_OUT] = h[:, 120:180, :]
// ---------------------------------------------------------------------------
__global__ void write_entity(const float* __restrict__ h, float* __restrict__ out) {
    int idx = blockIdx.x;           // 0 .. B*NE-1
    int t = threadIdx.x;            // 128 threads, 7 each
    int b = idx / NE_, e = idx % NE_;
    const float* src = h + (size_t)(b * N_NODE + NM_ + e) * D_;
    float* dst = out + (size_t)idx * D_;
    #pragma unroll
    for (int k = 0; k < 7; k++) dst[t + k * 128] = src[t + k * 128];
}

// ---------------------------------------------------------------------------
extern "C" void kernel_launch(void* const* d_in, const int* in_sizes, int n_in,
                              void* d_out, int out_size, void* d_ws, size_t ws_size,
                              hipStream_t stream) {
    const float* men = (const float*)d_in[0];
    const float* ent = (const float*)d_in[1];
    const float* sen = (const float*)d_in[2];
    const float* vir = (const float*)d_in[3];
    const float* te  = (const float*)d_in[4];
    const float* gw  = (const float*)d_in[5];
    const int* esrc  = (const int*)d_in[6];
    const int* edst  = (const int*)d_in[7];
    float* out = (float*)d_out;
    float* h = out + ENT_OUT;       // the "out" tuple element doubles as the h buffer

    // workspace layout
    char* ws = (char*)d_ws;
    size_t hbytes  = (size_t)N_TOTAL * D_ * sizeof(float);            // 45,875,200
    size_t sbytes  = (size_t)N_TOTAL * D_ * sizeof(ushort);           // 22,937,600
    size_t wtbytes = (size_t)NUM_LAYERS * D_ * D_ * sizeof(ushort);   // 6,422,528
    float* h0    = (float*)ws;                ws += hbytes;
    ushort* shi  = (ushort*)ws;               ws += sbytes;
    ushort* slo  = (ushort*)ws;               ws += sbytes;
    ushort* wthi = (ushort*)ws;               ws += wtbytes;
    ushort* wtlo = (ushort*)ws;               ws += wtbytes;
    int* cnt     = (int*)ws;                  ws += N_TOTAL * sizeof(int);
    int* cursor  = (int*)ws;                  ws += N_TOTAL * sizeof(int);
    int* offs    = (int*)ws;                  ws += (N_TOTAL + 1) * sizeof(int);
    int* csr     = (int*)ws;                  ws += (size_t)N_EDGE * sizeof(int);
    float* dis   = (float*)ws;                ws += N_TOTAL * sizeof(float);

    hipMemsetAsync(cnt, 0, 2 * N_TOTAL * sizeof(int), stream);   // cnt + cursor contiguous

    make_wt<<<NUM_LAYERS * 196, 256, 0, stream>>>(gw, wthi, wtlo);
    build_nodes<<<N_TOTAL, 128, 0, stream>>>(men, ent, sen, vir, te, h0);
    count_deg<<<(N_EDGE + 255) / 256, 256, 0, stream>>>(edst, cnt);
    scan_kernel<<<1, 1024, 0, stream>>>(cnt, offs, dis);
    fill_csr<<<(N_EDGE + 255) / 256, 256, 0, stream>>>(esrc, edst, offs, cursor, csr);

    for (int l = 0; l < NUM_LAYERS; l++) {
        double beta_d = log(0.5 / (l + 1) + 1.0);
        float beta = (float)beta_d;
        float bcoef = (float)(1.0 - beta_d);
        const float* hin = (l == 0) ? h0 : h;
        spmm_support<<<N_TOTAL, 256, 0, stream>>>(hin, h0, dis, offs, csr, shi, slo);
        gemm_mfma<<<100 * 7, 256, 0, stream>>>(shi, slo, wthi + (size_t)l * D_ * D_,
                                               wtlo + (size_t)l * D_ * D_, h, bcoef, beta);
    }
    write_entity<<<B_ * NE_, 128, 0, stream>>>(h, out);
}

// Round 12
// 1267.032 us; speedup vs baseline: 1.1569x; 1.0768x over previous
//
#include <hip/hip_runtime.h>
#include <hip/hip_bf16.h>
#include <math.h>

#define B_ 64
#define NM_ 120
#define NE_ 60
#define NS_ 18
#define NV_ 2
#define N_NODE 200
#define N_TOTAL 12800
#define D_ENC 768
#define D_TYPE 128
#define D_ 896
#define HALF_D 448
#define N_EDGE 409600
#define NUM_LAYERS 4
#define ENT_OUT (B_ * NE_ * D_)   // 3,440,640 floats

typedef __attribute__((ext_vector_type(8))) short short8v;   // 8 bf16 = 4 VGPR
typedef __attribute__((ext_vector_type(4))) float f32x4;

// fp32 -> bf16 round-to-nearest-even (bits)
__device__ __forceinline__ ushort f2bf_rne(float x) {
    unsigned u = __builtin_bit_cast(unsigned, x);
    unsigned r = (u + 0x7FFFu + ((u >> 16) & 1u)) >> 16;
    return (ushort)r;
}
__device__ __forceinline__ float bf2f(ushort h) {
    unsigned u = ((unsigned)h) << 16;
    return __builtin_bit_cast(float, u);
}

// ---------------------------------------------------------------------------
// 1. Build node features h0 = concat(hidden, type_emb)  (12800 x 896)
// ---------------------------------------------------------------------------
__global__ void build_nodes(const float* __restrict__ men, const float* __restrict__ ent,
                            const float* __restrict__ sen, const float* __restrict__ vir,
                            const float* __restrict__ te, float* __restrict__ h0) {
    int i = blockIdx.x;            // node id 0..12799
    int t = threadIdx.x;           // 128 threads, 7 elems each
    int b = i / N_NODE, n = i % N_NODE;
    const float* src; int typ;
    if (n < NM_)            { src = men + (size_t)(b * NM_ + n) * D_ENC;          typ = 0; }
    else if (n < NM_ + NE_) { src = ent + (size_t)(b * NE_ + (n - NM_)) * D_ENC;  typ = 1; }
    else if (n < NM_ + NE_ + NS_) { src = sen + (size_t)(b * NS_ + (n - NM_ - NE_)) * D_ENC; typ = 2; }
    else                    { src = vir + (size_t)(b * NV_ + (n - NM_ - NE_ - NS_)) * D_ENC; typ = 3; }
    float* o = h0 + (size_t)i * D_;
    #pragma unroll
    for (int k = 0; k < 7; k++) {
        int d = t + k * 128;
        float v = (d < D_ENC) ? src[d] : te[typ * D_TYPE + (d - D_ENC)];
        o[d] = v;
    }
}

// ---------------------------------------------------------------------------
// 2. CSR construction: degree histogram -> scan -> scatter
// ---------------------------------------------------------------------------
__global__ void count_deg(const int* __restrict__ dst, int* __restrict__ cnt) {
    int e = blockIdx.x * 256 + threadIdx.x;
    if (e < N_EDGE) atomicAdd(&cnt[dst[e]], 1);
}

__global__ void scan_kernel(const int* __restrict__ cnt, int* __restrict__ offs,
                            float* __restrict__ dis) {
    __shared__ int lds[1024];
    int t = threadIdx.x;
    int base = t * 13;
    int local[13];
    int sum = 0;
    #pragma unroll
    for (int k = 0; k < 13; k++) {
        int idx = base + k;
        int v = (idx < N_TOTAL) ? cnt[idx] : 0;
        local[k] = sum;
        sum += v;
    }
    lds[t] = sum;
    __syncthreads();
    for (int off = 1; off < 1024; off <<= 1) {
        int v = lds[t];
        int add = (t >= off) ? lds[t - off] : 0;
        __syncthreads();
        lds[t] = v + add;
        __syncthreads();
    }
    int excl = lds[t] - sum;
    #pragma unroll
    for (int k = 0; k < 13; k++) {
        int idx = base + k;
        if (idx < N_TOTAL) {
            offs[idx] = excl + local[k];
            dis[idx] = rsqrtf((float)(cnt[idx] + 1));   // deg includes self loop
        }
    }
    if (t == 1023) offs[N_TOTAL] = excl + sum;
}

__global__ void fill_csr(const int* __restrict__ src, const int* __restrict__ dst,
                         const int* __restrict__ offs, int* __restrict__ cursor,
                         int* __restrict__ csr_src) {
    int e = blockIdx.x * 256 + threadIdx.x;
    if (e < N_EDGE) {
        int d = dst[e];
        int pos = atomicAdd(&cursor[d], 1);
        csr_src[offs[d] + pos] = src[e];
    }
}

// ---------------------------------------------------------------------------
// 2b. W^T split: WT_hi/lo[l][n][k] (bf16) from W[l][k][n] (fp32), LDS-tiled
// ---------------------------------------------------------------------------
__global__ __launch_bounds__(256) void make_wt(const float* __restrict__ W,
                                               ushort* __restrict__ WT_hi,
                                               ushort* __restrict__ WT_lo) {
    __shared__ float lds[64][65];
    int bid = blockIdx.x;
    int l = bid / 196; int rem = bid % 196;
    int tk = rem / 14, tn = rem % 14;
    const float* Wl = W + (size_t)l * D_ * D_;
    int t = threadIdx.x;
    #pragma unroll
    for (int q = 0; q < 16; q++) {
        int id = q * 256 + t;
        int kk = id >> 6, nn = id & 63;
        lds[kk][nn] = Wl[(size_t)(tk * 64 + kk) * D_ + tn * 64 + nn];
    }
    __syncthreads();
    #pragma unroll
    for (int q = 0; q < 16; q++) {
        int id = q * 256 + t;
        int nn = id >> 6, kk = id & 63;
        float x = lds[kk][nn];
        ushort hi = f2bf_rne(x);
        ushort lo = f2bf_rne(x - bf2f(hi));
        size_t o = (size_t)l * D_ * D_ + (size_t)(tn * 64 + nn) * D_ + tk * 64 + kk;
        WT_hi[o] = hi; WT_lo[o] = lo;
    }
}

// ---------------------------------------------------------------------------
// 3. SpMM + support, D-SPLIT 2-pass (r11): pass p handles cols [p*448,(p+1)*448).
//    Pass-major block order halves the live gather working set (45.9->22.9 MB)
//    to raise L2 hit rate (r10: FETCH 702 MB = ~52% hit, capacity-thrash).
//    S output = hi/lo bf16 split.  128 thr/block, 112 active (448 f32 = 112 f4).
// ---------------------------------------------------------------------------
__global__ __launch_bounds__(128) void spmm_support(
        const float* __restrict__ hin, const float* __restrict__ h0,
        const float* __restrict__ dis, const int* __restrict__ offs,
        const int* __restrict__ csr_src,
        ushort* __restrict__ S_hi, ushort* __restrict__ S_lo) {
    int b0 = blockIdx.x;
    int pass = b0 / N_TOTAL;            // 0,1 — pass-major for temporal phase split
    int i = b0 - pass * N_TOTAL;
    int t = threadIdx.x;
    __shared__ int s_idx[128];
    __shared__ float s_w[128];
    int e0 = offs[i], e1 = offs[i + 1];
    float di = dis[i];
    bool active = t < 112;
    int dbase = pass * HALF_D;
    float4 acc = make_float4(0.f, 0.f, 0.f, 0.f);
    if (active) {
        float4 hv = ((const float4*)(hin + (size_t)i * D_ + dbase))[t];   // self loop
        acc.x = di * hv.x; acc.y = di * hv.y; acc.z = di * hv.z; acc.w = di * hv.w;
    }
    for (int c = e0; c < e1; c += 128) {
        int n = e1 - c; if (n > 128) n = 128;
        if (t < n) { int s = csr_src[c + t]; s_idx[t] = s; s_w[t] = dis[s]; }
        __syncthreads();
        if (active) {
            #pragma unroll 8
            for (int j = 0; j < n; j++) {
                const float4* hp = (const float4*)(hin + (size_t)s_idx[j] * D_ + dbase);
                float w = s_w[j];
                float4 hv = hp[t];
                acc.x += w * hv.x; acc.y += w * hv.y;
                acc.z += w * hv.z; acc.w += w * hv.w;
            }
        }
        __syncthreads();
    }
    if (active) {
        f32x4 h0v = __builtin_nontemporal_load((const f32x4*)(h0 + (size_t)i * D_ + dbase) + t);
        float ox = 0.9f * di * acc.x + 0.1f * h0v[0];
        float oy = 0.9f * di * acc.y + 0.1f * h0v[1];
        float oz = 0.9f * di * acc.z + 0.1f * h0v[2];
        float ow = 0.9f * di * acc.w + 0.1f * h0v[3];
        ushort hx = f2bf_rne(ox), hy = f2bf_rne(oy), hz = f2bf_rne(oz), hw = f2bf_rne(ow);
        ushort lx = f2bf_rne(ox - bf2f(hx)), ly = f2bf_rne(oy - bf2f(hy));
        ushort lz = f2bf_rne(oz - bf2f(hz)), lw = f2bf_rne(ow - bf2f(hw));
        *(ushort4*)(S_hi + (size_t)i * D_ + dbase + 4 * t) = make_ushort4(hx, hy, hz, hw);
        *(ushort4*)(S_lo + (size_t)i * D_ + dbase + 4 * t) = make_ushort4(lx, ly, lz, lw);
    }
}

// ---------------------------------------------------------------------------
// 4. Split-bf16 MFMA GEMM + affine + relu (unchanged from r10: ~105 us/disp).
// ---------------------------------------------------------------------------
__global__ __launch_bounds__(256) void gemm_mfma(
        const ushort* __restrict__ S_hi, const ushort* __restrict__ S_lo,
        const ushort* __restrict__ WT_hi, const ushort* __restrict__ WT_lo,
        float* __restrict__ H, float bcoef, float beta) {
    __shared__ __align__(16) ushort As_hi[128 * 40];
    __shared__ __align__(16) ushort As_lo[128 * 40];
    __shared__ __align__(16) ushort Bs_hi[128 * 40];
    __shared__ __align__(16) ushort Bs_lo[128 * 40];

    int t = threadIdx.x;
    int b0 = blockIdx.x;
    int xcd = b0 & 7, pos = b0 >> 3;                       // grid=700, 700%8!=0:
    int wgid = (xcd < 4 ? xcd * 88 : 352 + (xcd - 4) * 87) + pos;  // bijective (m204)
    int tile_n = wgid % 7;
    int tile_m = wgid / 7;
    int row0 = tile_m * 128, col0 = tile_n * 128;

    int lane = t & 63, w = t >> 6;
    int wm = w >> 1, wn = w & 1;          // 2x2 wave grid, each 64x64 output
    int lrow = lane & 15, lg = lane >> 4; // MFMA fragment coords

    f32x4 acc[4][4];
    #pragma unroll
    for (int i = 0; i < 4; i++)
        #pragma unroll
        for (int j = 0; j < 4; j++) acc[i][j] = (f32x4){0.f, 0.f, 0.f, 0.f};

    for (int k0 = 0; k0 < D_; k0 += 32) {
        // ---- stage A: 128 rows x 32 k bf16 hi/lo, layout [m][40] (pad kills conflicts)
        #pragma unroll
        for (int q = 0; q < 2; q++) {
            int id = q * 256 + t;          // 0..511
            int r = id >> 2;               // row 0..127
            int seg = id & 3;              // 8-bf16 segment
            size_t g = (size_t)(row0 + r) * D_ + k0 + seg * 8;
            int o = r * 40 + seg * 8;
            *(short8v*)&As_hi[o] = *(const short8v*)(S_hi + g);
            *(short8v*)&As_lo[o] = *(const short8v*)(S_lo + g);
        }
        // ---- stage B: WT [n][k] bf16 hi/lo, layout [n][40]
        #pragma unroll
        for (int q = 0; q < 2; q++) {
            int id = q * 256 + t;
            int r = id >> 2;
            int seg = id & 3;
            size_t g = (size_t)(col0 + r) * D_ + k0 + seg * 8;
            int o = r * 40 + seg * 8;
            *(short8v*)&Bs_hi[o] = *(const short8v*)(WT_hi + g);
            *(short8v*)&Bs_lo[o] = *(const short8v*)(WT_lo + g);
        }
        __syncthreads();

        // ---- compute: 48 MFMA per wave per k-step
        short8v a_hi[4], a_lo[4];
        #pragma unroll
        for (int fm = 0; fm < 4; fm++) {
            int o = (wm * 64 + fm * 16 + lrow) * 40 + lg * 8;
            a_hi[fm] = *(const short8v*)&As_hi[o];
            a_lo[fm] = *(const short8v*)&As_lo[o];
        }
        #pragma unroll
        for (int fn = 0; fn < 4; fn++) {
            int o = (wn * 64 + fn * 16 + lrow) * 40 + lg * 8;
            short8v b_hi = *(const short8v*)&Bs_hi[o];
            short8v b_lo = *(const short8v*)&Bs_lo[o];
            #pragma unroll
            for (int fm = 0; fm < 4; fm++) {
                acc[fm][fn] = __builtin_amdgcn_mfma_f32_16x16x32_bf16(a_hi[fm], b_hi, acc[fm][fn], 0, 0, 0);
                acc[fm][fn] = __builtin_amdgcn_mfma_f32_16x16x32_bf16(a_hi[fm], b_lo, acc[fm][fn], 0, 0, 0);
                acc[fm][fn] = __builtin_amdgcn_mfma_f32_16x16x32_bf16(a_lo[fm], b_hi, acc[fm][fn], 0, 0, 0);
            }
        }
        __syncthreads();
    }

    // ---- epilogue: relu((1-beta)*(hi+lo) + beta*acc)
    // C/D layout (HW-verified): row = lg*4 + reg, col = lrow
    #pragma unroll
    for (int fm = 0; fm < 4; fm++) {
        #pragma unroll
        for (int fn = 0; fn < 4; fn++) {
            #pragma unroll
            for (int r = 0; r < 4; r++) {
                int m = row0 + wm * 64 + fm * 16 + lg * 4 + r;
                int n = col0 + wn * 64 + fn * 16 + lrow;
                size_t off = (size_t)m * D_ + n;
                float sv = bf2f(S_hi[off]) + bf2f(S_lo[off]);
                H[off] = fmaxf(bcoef * sv + beta * acc[fm][fn][r], 0.f);
            }
        }
    }
}

// ---------------------------------------------------------------------------
// 5. Entity slice: out[:ENT_OUT] = h[:, 120:180, :]
// ---------------------------------------------------------------------------
__global__ void write_entity(const float* __restrict__ h, float* __restrict__ out) {
    int idx = blockIdx.x;           // 0 .. B*NE-1
    int t = threadIdx.x;            // 128 threads, 7 each
    int b = idx / NE_, e = idx % NE_;
    const float* src = h + (size_t)(b * N_NODE + NM_ + e) * D_;
    float* dst = out + (size_t)idx * D_;
    #pragma unroll
    for (int k = 0; k < 7; k++) dst[t + k * 128] = src[t + k * 128];
}

// ---------------------------------------------------------------------------
extern "C" void kernel_launch(void* const* d_in, const int* in_sizes, int n_in,
                              void* d_out, int out_size, void* d_ws, size_t ws_size,
                              hipStream_t stream) {
    const float* men = (const float*)d_in[0];
    const float* ent = (const float*)d_in[1];
    const float* sen = (const float*)d_in[2];
    const float* vir = (const float*)d_in[3];
    const float* te  = (const float*)d_in[4];
    const float* gw  = (const float*)d_in[5];
    const int* esrc  = (const int*)d_in[6];
    const int* edst  = (const int*)d_in[7];
    float* out = (float*)d_out;
    float* h = out + ENT_OUT;       // the "out" tuple element doubles as the h buffer

    // workspace layout
    char* ws = (char*)d_ws;
    size_t hbytes  = (size_t)N_TOTAL * D_ * sizeof(float);            // 45,875,200
    size_t sbytes  = (size_t)N_TOTAL * D_ * sizeof(ushort);           // 22,937,600
    size_t wtbytes = (size_t)NUM_LAYERS * D_ * D_ * sizeof(ushort);   // 6,422,528
    float* h0    = (float*)ws;                ws += hbytes;
    ushort* shi  = (ushort*)ws;               ws += sbytes;
    ushort* slo  = (ushort*)ws;               ws += sbytes;
    ushort* wthi = (ushort*)ws;               ws += wtbytes;
    ushort* wtlo = (ushort*)ws;               ws += wtbytes;
    int* cnt     = (int*)ws;                  ws += N_TOTAL * sizeof(int);
    int* cursor  = (int*)ws;                  ws += N_TOTAL * sizeof(int);
    int* offs    = (int*)ws;                  ws += (N_TOTAL + 1) * sizeof(int);
    int* csr     = (int*)ws;                  ws += (size_t)N_EDGE * sizeof(int);
    float* dis   = (float*)ws;                ws += N_TOTAL * sizeof(float);

    hipMemsetAsync(cnt, 0, 2 * N_TOTAL * sizeof(int), stream);   // cnt + cursor contiguous

    make_wt<<<NUM_LAYERS * 196, 256, 0, stream>>>(gw, wthi, wtlo);
    build_nodes<<<N_TOTAL, 128, 0, stream>>>(men, ent, sen, vir, te, h0);
    count_deg<<<(N_EDGE + 255) / 256, 256, 0, stream>>>(edst, cnt);
    scan_kernel<<<1, 1024, 0, stream>>>(cnt, offs, dis);
    fill_csr<<<(N_EDGE + 255) / 256, 256, 0, stream>>>(esrc, edst, offs, cursor, csr);

    for (int l = 0; l < NUM_LAYERS; l++) {
        double beta_d = log(0.5 / (l + 1) + 1.0);
        float beta = (float)beta_d;
        float bcoef = (float)(1.0 - beta_d);
        const float* hin = (l == 0) ? h0 : h;
        spmm_support<<<2 * N_TOTAL, 128, 0, stream>>>(hin, h0, dis, offs, csr, shi, slo);
        gemm_mfma<<<100 * 7, 256, 0, stream>>>(shi, slo, wthi + (size_t)l * D_ * D_,
                                               wtlo + (size_t)l * D_ * D_, h, bcoef, beta);
    }
    write_entity<<<B_ * NE_, 128, 0, stream>>>(h, out);
}

// Round 13
// 873.127 us; speedup vs baseline: 1.6789x; 1.4511x over previous
//
#include <hip/hip_runtime.h>
#include <hip/hip_bf16.h>
#include <math.h>

#define B_ 64
#define NM_ 120
#define NE_ 60
#define NS_ 18
#define NV_ 2
#define N_NODE 200
#define N_TOTAL 12800
#define D_ENC 768
#define D_TYPE 128
#define D_ 896
#define HALF_D 448
#define N_EDGE 409600
#define NUM_LAYERS 4
#define ENT_OUT (B_ * NE_ * D_)   // 3,440,640 floats

typedef __attribute__((ext_vector_type(8))) short short8v;   // 8 bf16 = 4 VGPR
typedef __attribute__((ext_vector_type(4))) float f32x4;

// fp32 -> bf16 round-to-nearest-even (bits)
__device__ __forceinline__ ushort f2bf_rne(float x) {
    unsigned u = __builtin_bit_cast(unsigned, x);
    unsigned r = (u + 0x7FFFu + ((u >> 16) & 1u)) >> 16;
    return (ushort)r;
}
__device__ __forceinline__ float bf2f(ushort h) {
    unsigned u = ((unsigned)h) << 16;
    return __builtin_bit_cast(float, u);
}

// ---------------------------------------------------------------------------
// 1. Build node features h0 = concat(hidden, type_emb), fp32 + bf16 gather copy
// ---------------------------------------------------------------------------
__global__ void build_nodes(const float* __restrict__ men, const float* __restrict__ ent,
                            const float* __restrict__ sen, const float* __restrict__ vir,
                            const float* __restrict__ te, float* __restrict__ h0,
                            ushort* __restrict__ h0bf) {
    int i = blockIdx.x;            // node id 0..12799
    int t = threadIdx.x;           // 128 threads, 7 elems each
    int b = i / N_NODE, n = i % N_NODE;
    const float* src; int typ;
    if (n < NM_)            { src = men + (size_t)(b * NM_ + n) * D_ENC;          typ = 0; }
    else if (n < NM_ + NE_) { src = ent + (size_t)(b * NE_ + (n - NM_)) * D_ENC;  typ = 1; }
    else if (n < NM_ + NE_ + NS_) { src = sen + (size_t)(b * NS_ + (n - NM_ - NE_)) * D_ENC; typ = 2; }
    else                    { src = vir + (size_t)(b * NV_ + (n - NM_ - NE_ - NS_)) * D_ENC; typ = 3; }
    float* o = h0 + (size_t)i * D_;
    ushort* ob = h0bf + (size_t)i * D_;
    #pragma unroll
    for (int k = 0; k < 7; k++) {
        int d = t + k * 128;
        float v = (d < D_ENC) ? src[d] : te[typ * D_TYPE + (d - D_ENC)];
        o[d] = v;
        ob[d] = f2bf_rne(v);
    }
}

// ---------------------------------------------------------------------------
// 2. CSR construction: degree histogram -> scan -> scatter
// ---------------------------------------------------------------------------
__global__ void count_deg(const int* __restrict__ dst, int* __restrict__ cnt) {
    int e = blockIdx.x * 256 + threadIdx.x;
    if (e < N_EDGE) atomicAdd(&cnt[dst[e]], 1);
}

__global__ void scan_kernel(const int* __restrict__ cnt, int* __restrict__ offs,
                            float* __restrict__ dis) {
    __shared__ int lds[1024];
    int t = threadIdx.x;
    int base = t * 13;
    int local[13];
    int sum = 0;
    #pragma unroll
    for (int k = 0; k < 13; k++) {
        int idx = base + k;
        int v = (idx < N_TOTAL) ? cnt[idx] : 0;
        local[k] = sum;
        sum += v;
    }
    lds[t] = sum;
    __syncthreads();
    for (int off = 1; off < 1024; off <<= 1) {
        int v = lds[t];
        int add = (t >= off) ? lds[t - off] : 0;
        __syncthreads();
        lds[t] = v + add;
        __syncthreads();
    }
    int excl = lds[t] - sum;
    #pragma unroll
    for (int k = 0; k < 13; k++) {
        int idx = base + k;
        if (idx < N_TOTAL) {
            offs[idx] = excl + local[k];
            dis[idx] = rsqrtf((float)(cnt[idx] + 1));   // deg includes self loop
        }
    }
    if (t == 1023) offs[N_TOTAL] = excl + sum;
}

__global__ void fill_csr(const int* __restrict__ src, const int* __restrict__ dst,
                         const int* __restrict__ offs, int* __restrict__ cursor,
                         int* __restrict__ csr_src) {
    int e = blockIdx.x * 256 + threadIdx.x;
    if (e < N_EDGE) {
        int d = dst[e];
        int pos = atomicAdd(&cursor[d], 1);
        csr_src[offs[d] + pos] = src[e];
    }
}

// ---------------------------------------------------------------------------
// 2b. W^T split: WT_hi/lo[l][n][k] (bf16) from W[l][k][n] (fp32), LDS-tiled
// ---------------------------------------------------------------------------
__global__ __launch_bounds__(256) void make_wt(const float* __restrict__ W,
                                               ushort* __restrict__ WT_hi,
                                               ushort* __restrict__ WT_lo) {
    __shared__ float lds[64][65];
    int bid = blockIdx.x;
    int l = bid / 196; int rem = bid % 196;
    int tk = rem / 14, tn = rem % 14;
    const float* Wl = W + (size_t)l * D_ * D_;
    int t = threadIdx.x;
    #pragma unroll
    for (int q = 0; q < 16; q++) {
        int id = q * 256 + t;
        int kk = id >> 6, nn = id & 63;
        lds[kk][nn] = Wl[(size_t)(tk * 64 + kk) * D_ + tn * 64 + nn];
    }
    __syncthreads();
    #pragma unroll
    for (int q = 0; q < 16; q++) {
        int id = q * 256 + t;
        int nn = id >> 6, kk = id & 63;
        float x = lds[kk][nn];
        ushort hi = f2bf_rne(x);
        ushort lo = f2bf_rne(x - bf2f(hi));
        size_t o = (size_t)l * D_ * D_ + (size_t)(tn * 64 + nn) * D_ + tk * 64 + kk;
        WT_hi[o] = hi; WT_lo[o] = lo;
    }
}

// ---------------------------------------------------------------------------
// 3. SpMM + support, 2-pass D-split, **bf16 gather table** (r13):
//    gather traffic halved (r12 showed dur tracks FETCH at ~3.5 TB/s fill).
//    Neighbor+self contributions from bf16 hbf (err ~2e-5 abs, see analysis);
//    0.1*h0 residual stays fp32. S output = hi/lo bf16 split of fp32 result.
// ---------------------------------------------------------------------------
__global__ __launch_bounds__(128) void spmm_support(
        const ushort* __restrict__ hbf, const float* __restrict__ h0,
        const float* __restrict__ dis, const int* __restrict__ offs,
        const int* __restrict__ csr_src,
        ushort* __restrict__ S_hi, ushort* __restrict__ S_lo) {
    int b0 = blockIdx.x;
    int pass = b0 / N_TOTAL;            // 0,1 — pass-major for temporal phase split
    int i = b0 - pass * N_TOTAL;
    int t = threadIdx.x;
    __shared__ int s_idx[128];
    __shared__ float s_w[128];
    int e0 = offs[i], e1 = offs[i + 1];
    float di = dis[i];
    bool active = t < 112;
    int dbase = pass * HALF_D;
    float4 acc = make_float4(0.f, 0.f, 0.f, 0.f);
    if (active) {
        ushort4 hv = *(const ushort4*)(hbf + (size_t)i * D_ + dbase + 4 * t);  // self loop
        acc.x = di * bf2f(hv.x); acc.y = di * bf2f(hv.y);
        acc.z = di * bf2f(hv.z); acc.w = di * bf2f(hv.w);
    }
    for (int c = e0; c < e1; c += 128) {
        int n = e1 - c; if (n > 128) n = 128;
        if (t < n) { int s = csr_src[c + t]; s_idx[t] = s; s_w[t] = dis[s]; }
        __syncthreads();
        if (active) {
            #pragma unroll 8
            for (int j = 0; j < n; j++) {
                ushort4 hv = *(const ushort4*)(hbf + (size_t)s_idx[j] * D_ + dbase + 4 * t);
                float w = s_w[j];
                acc.x += w * bf2f(hv.x); acc.y += w * bf2f(hv.y);
                acc.z += w * bf2f(hv.z); acc.w += w * bf2f(hv.w);
            }
        }
        __syncthreads();
    }
    if (active) {
        f32x4 h0v = __builtin_nontemporal_load((const f32x4*)(h0 + (size_t)i * D_ + dbase) + t);
        float ox = 0.9f * di * acc.x + 0.1f * h0v[0];
        float oy = 0.9f * di * acc.y + 0.1f * h0v[1];
        float oz = 0.9f * di * acc.z + 0.1f * h0v[2];
        float ow = 0.9f * di * acc.w + 0.1f * h0v[3];
        ushort hx = f2bf_rne(ox), hy = f2bf_rne(oy), hz = f2bf_rne(oz), hw = f2bf_rne(ow);
        ushort lx = f2bf_rne(ox - bf2f(hx)), ly = f2bf_rne(oy - bf2f(hy));
        ushort lz = f2bf_rne(oz - bf2f(hz)), lw = f2bf_rne(ow - bf2f(hw));
        *(ushort4*)(S_hi + (size_t)i * D_ + dbase + 4 * t) = make_ushort4(hx, hy, hz, hw);
        *(ushort4*)(S_lo + (size_t)i * D_ + dbase + 4 * t) = make_ushort4(lx, ly, lz, lw);
    }
}

// ---------------------------------------------------------------------------
// 4. Split-bf16 MFMA GEMM + affine + relu. LAST=false: write bf16 hbf only
//    (next layer's gather table; -23 MB write). LAST=true: write fp32 h (output).
// ---------------------------------------------------------------------------
template <bool LAST>
__global__ __launch_bounds__(256) void gemm_mfma(
        const ushort* __restrict__ S_hi, const ushort* __restrict__ S_lo,
        const ushort* __restrict__ WT_hi, const ushort* __restrict__ WT_lo,
        float* __restrict__ H, ushort* __restrict__ Hbf,
        float bcoef, float beta) {
    __shared__ __align__(16) ushort As_hi[128 * 40];
    __shared__ __align__(16) ushort As_lo[128 * 40];
    __shared__ __align__(16) ushort Bs_hi[128 * 40];
    __shared__ __align__(16) ushort Bs_lo[128 * 40];

    int t = threadIdx.x;
    int b0 = blockIdx.x;
    int xcd = b0 & 7, pos = b0 >> 3;                       // grid=700, 700%8!=0:
    int wgid = (xcd < 4 ? xcd * 88 : 352 + (xcd - 4) * 87) + pos;  // bijective (m204)
    int tile_n = wgid % 7;
    int tile_m = wgid / 7;
    int row0 = tile_m * 128, col0 = tile_n * 128;

    int lane = t & 63, w = t >> 6;
    int wm = w >> 1, wn = w & 1;          // 2x2 wave grid, each 64x64 output
    int lrow = lane & 15, lg = lane >> 4; // MFMA fragment coords

    f32x4 acc[4][4];
    #pragma unroll
    for (int i = 0; i < 4; i++)
        #pragma unroll
        for (int j = 0; j < 4; j++) acc[i][j] = (f32x4){0.f, 0.f, 0.f, 0.f};

    for (int k0 = 0; k0 < D_; k0 += 32) {
        // ---- stage A: 128 rows x 32 k bf16 hi/lo, layout [m][40] (pad kills conflicts)
        #pragma unroll
        for (int q = 0; q < 2; q++) {
            int id = q * 256 + t;          // 0..511
            int r = id >> 2;               // row 0..127
            int seg = id & 3;              // 8-bf16 segment
            size_t g = (size_t)(row0 + r) * D_ + k0 + seg * 8;
            int o = r * 40 + seg * 8;
            *(short8v*)&As_hi[o] = *(const short8v*)(S_hi + g);
            *(short8v*)&As_lo[o] = *(const short8v*)(S_lo + g);
        }
        // ---- stage B: WT [n][k] bf16 hi/lo, layout [n][40]
        #pragma unroll
        for (int q = 0; q < 2; q++) {
            int id = q * 256 + t;
            int r = id >> 2;
            int seg = id & 3;
            size_t g = (size_t)(col0 + r) * D_ + k0 + seg * 8;
            int o = r * 40 + seg * 8;
            *(short8v*)&Bs_hi[o] = *(const short8v*)(WT_hi + g);
            *(short8v*)&Bs_lo[o] = *(const short8v*)(WT_lo + g);
        }
        __syncthreads();

        // ---- compute: 48 MFMA per wave per k-step
        short8v a_hi[4], a_lo[4];
        #pragma unroll
        for (int fm = 0; fm < 4; fm++) {
            int o = (wm * 64 + fm * 16 + lrow) * 40 + lg * 8;
            a_hi[fm] = *(const short8v*)&As_hi[o];
            a_lo[fm] = *(const short8v*)&As_lo[o];
        }
        #pragma unroll
        for (int fn = 0; fn < 4; fn++) {
            int o = (wn * 64 + fn * 16 + lrow) * 40 + lg * 8;
            short8v b_hi = *(const short8v*)&Bs_hi[o];
            short8v b_lo = *(const short8v*)&Bs_lo[o];
            #pragma unroll
            for (int fm = 0; fm < 4; fm++) {
                acc[fm][fn] = __builtin_amdgcn_mfma_f32_16x16x32_bf16(a_hi[fm], b_hi, acc[fm][fn], 0, 0, 0);
                acc[fm][fn] = __builtin_amdgcn_mfma_f32_16x16x32_bf16(a_hi[fm], b_lo, acc[fm][fn], 0, 0, 0);
                acc[fm][fn] = __builtin_amdgcn_mfma_f32_16x16x32_bf16(a_lo[fm], b_hi, acc[fm][fn], 0, 0, 0);
            }
        }
        __syncthreads();
    }

    // ---- epilogue: relu((1-beta)*(hi+lo) + beta*acc)
    // C/D layout (HW-verified): row = lg*4 + reg, col = lrow
    #pragma unroll
    for (int fm = 0; fm < 4; fm++) {
        #pragma unroll
        for (int fn = 0; fn < 4; fn++) {
            #pragma unroll
            for (int r = 0; r < 4; r++) {
                int m = row0 + wm * 64 + fm * 16 + lg * 4 + r;
                int n = col0 + wn * 64 + fn * 16 + lrow;
                size_t off = (size_t)m * D_ + n;
                float sv = bf2f(S_hi[off]) + bf2f(S_lo[off]);
                float hv = fmaxf(bcoef * sv + beta * acc[fm][fn][r], 0.f);
                if (LAST) H[off] = hv;
                else      Hbf[off] = f2bf_rne(hv);
            }
        }
    }
}

// ---------------------------------------------------------------------------
// 5. Entity slice: out[:ENT_OUT] = h[:, 120:180, :]
// ---------------------------------------------------------------------------
__global__ void write_entity(const float* __restrict__ h, float* __restrict__ out) {
    int idx = blockIdx.x;           // 0 .. B*NE-1
    int t = threadIdx.x;            // 128 threads, 7 each
    int b = idx / NE_, e = idx % NE_;
    const float* src = h + (size_t)(b * N_NODE + NM_ + e) * D_;
    float* dst = out + (size_t)idx * D_;
    #pragma unroll
    for (int k = 0; k < 7; k++) dst[t + k * 128] = src[t + k * 128];
}

// ---------------------------------------------------------------------------
extern "C" void kernel_launch(void* const* d_in, const int* in_sizes, int n_in,
                              void* d_out, int out_size, void* d_ws, size_t ws_size,
                              hipStream_t stream) {
    const float* men = (const float*)d_in[0];
    const float* ent = (const float*)d_in[1];
    const float* sen = (const float*)d_in[2];
    const float* vir = (const float*)d_in[3];
    const float* te  = (const float*)d_in[4];
    const float* gw  = (const float*)d_in[5];
    const int* esrc  = (const int*)d_in[6];
    const int* edst  = (const int*)d_in[7];
    float* out = (float*)d_out;
    float* h = out + ENT_OUT;       // the "out" tuple element doubles as the h buffer

    // workspace layout
    char* ws = (char*)d_ws;
    size_t hbytes  = (size_t)N_TOTAL * D_ * sizeof(float);            // 45,875,200
    size_t sbytes  = (size_t)N_TOTAL * D_ * sizeof(ushort);           // 22,937,600
    size_t wtbytes = (size_t)NUM_LAYERS * D_ * D_ * sizeof(ushort);   // 6,422,528
    float* h0    = (float*)ws;                ws += hbytes;
    ushort* h0bf = (ushort*)ws;               ws += sbytes;
    ushort* hbf  = (ushort*)ws;               ws += sbytes;
    ushort* shi  = (ushort*)ws;               ws += sbytes;
    ushort* slo  = (ushort*)ws;               ws += sbytes;
    ushort* wthi = (ushort*)ws;               ws += wtbytes;
    ushort* wtlo = (ushort*)ws;               ws += wtbytes;
    int* cnt     = (int*)ws;                  ws += N_TOTAL * sizeof(int);
    int* cursor  = (int*)ws;                  ws += N_TOTAL * sizeof(int);
    int* offs    = (int*)ws;                  ws += (N_TOTAL + 1) * sizeof(int);
    int* csr     = (int*)ws;                  ws += (size_t)N_EDGE * sizeof(int);
    float* dis   = (float*)ws;                ws += N_TOTAL * sizeof(float);

    hipMemsetAsync(cnt, 0, 2 * N_TOTAL * sizeof(int), stream);   // cnt + cursor contiguous

    make_wt<<<NUM_LAYERS * 196, 256, 0, stream>>>(gw, wthi, wtlo);
    build_nodes<<<N_TOTAL, 128, 0, stream>>>(men, ent, sen, vir, te, h0, h0bf);
    count_deg<<<(N_EDGE + 255) / 256, 256, 0, stream>>>(edst, cnt);
    scan_kernel<<<1, 1024, 0, stream>>>(cnt, offs, dis);
    fill_csr<<<(N_EDGE + 255) / 256, 256, 0, stream>>>(esrc, edst, offs, cursor, csr);

    for (int l = 0; l < NUM_LAYERS; l++) {
        double beta_d = log(0.5 / (l + 1) + 1.0);
        float beta = (float)beta_d;
        float bcoef = (float)(1.0 - beta_d);
        const ushort* gtab = (l == 0) ? h0bf : hbf;
        spmm_support<<<2 * N_TOTAL, 128, 0, stream>>>(gtab, h0, dis, offs, csr, shi, slo);
        if (l < NUM_LAYERS - 1)
            gemm_mfma<false><<<100 * 7, 256, 0, stream>>>(shi, slo, wthi + (size_t)l * D_ * D_,
                                                          wtlo + (size_t)l * D_ * D_, h, hbf, bcoef, beta);
        else
            gemm_mfma<true><<<100 * 7, 256, 0, stream>>>(shi, slo, wthi + (size_t)l * D_ * D_,
                                                         wtlo + (size_t)l * D_ * D_, h, hbf, bcoef, beta);
    }
    write_entity<<<B_ * NE_, 128, 0, stream>>>(h, out);
}